// Round 3
// baseline (503.718 us; speedup 1.0000x reference)
//
#include <hip/hip_runtime.h>

typedef __bf16 bf16x8 __attribute__((ext_vector_type(8)));
typedef float  f32x16 __attribute__((ext_vector_type(16)));

#define LOG2E 1.4426950408889634f

static __device__ __forceinline__ float fexp2(float x) { return __builtin_amdgcn_exp2f(x); }
static __device__ __forceinline__ float frcp(float x)  { return __builtin_amdgcn_rcpf(x); }
static __device__ __forceinline__ float fsigmoid(float x) { return frcp(1.0f + fexp2(-LOG2E * x)); }
static __device__ __forceinline__ float ftanh(float x)    { return 2.0f * frcp(1.0f + fexp2(-2.0f * LOG2E * x)) - 1.0f; }

// ---------------------------------------------------------------------------
// Prep: pack 4 [512x512] fp32 weights into bf16 MFMA-B-fragment-coalesced layout.
// Wp[((g*16+cb)*32+kk)*512 + lane*8 + e] = W_g[cb*32+(lane&31)][kk*16+(lane>>5)*8+e]
// ---------------------------------------------------------------------------
__global__ __launch_bounds__(256) void wpack(const float* __restrict__ Wf,
                                             const float* __restrict__ Wi,
                                             const float* __restrict__ Wg,
                                             const float* __restrict__ Wo,
                                             __bf16* __restrict__ Wp)
{
    int idx = blockIdx.x * 256 + threadIdx.x;      // [0, 131072)
    int kg  = idx & 63;                            // k-group of 8
    int j   = (idx >> 6) & 511;                    // weight row = output col
    int g   = idx >> 15;
    const float* src = (g == 0) ? Wf : (g == 1) ? Wi : (g == 2) ? Wg : Wo;
    const float4* s4 = (const float4*)(src + j * 512 + kg * 8);
    float4 v0 = s4[0], v1 = s4[1];
    bf16x8 o;
    o[0] = (__bf16)v0.x; o[1] = (__bf16)v0.y; o[2] = (__bf16)v0.z; o[3] = (__bf16)v0.w;
    o[4] = (__bf16)v1.x; o[5] = (__bf16)v1.y; o[6] = (__bf16)v1.z; o[7] = (__bf16)v1.w;
    int cb = j >> 5;
    int kk = kg >> 1;
    int lane_t = (j & 31) + (kg & 1) * 32;
    size_t dst = ((size_t)((g * 16 + cb) * 32 + kk)) * 512 + lane_t * 8;
    *(bf16x8*)(Wp + dst) = o;
}

// ---------------------------------------------------------------------------
// Main fused kernel. Block: 256 thr (4 waves), 64 rows.
// LDS holds z in A-fragment order; inner loop is an explicit 2-deep
// software pipeline (register double-buffered A and B fragments).
// ---------------------------------------------------------------------------
__global__ __launch_bounds__(256, 2) void lstm_main(
    const float* __restrict__ xin, const float* __restrict__ stm,
    const __bf16* __restrict__ Wp,
    const float* __restrict__ bfv, const float* __restrict__ biv,
    const float* __restrict__ bgv, const float* __restrict__ bov,
    float* __restrict__ out)
{
    __shared__ unsigned char zs[65536];            // 64 rows x 512 k, bf16, frag order
    const int tid  = threadIdx.x;
    const int lane = tid & 63;
    const int wv   = tid >> 6;                     // 0..3
    const int l31  = lane & 31;
    const int hi   = lane >> 5;
    const int row0 = blockIdx.x * 64;

    // ---- phase 0: z = x + stm -> bf16 -> LDS in fragment order ----
    {
        const float* xb = xin + (size_t)row0 * 512;
        const float* sb = stm + (size_t)row0 * 512;
        #pragma unroll
        for (int it = 0; it < 16; ++it) {
            int idx = it * 256 + tid;              // [0, 4096): 64 rows x 64 kgroups
            int row = idx >> 6;
            int kg  = idx & 63;
            const float4* x4 = (const float4*)(xb + row * 512 + kg * 8);
            const float4* s4 = (const float4*)(sb + row * 512 + kg * 8);
            float4 a0 = x4[0], a1 = x4[1];
            float4 b0 = s4[0], b1 = s4[1];
            bf16x8 p;
            p[0] = (__bf16)(a0.x + b0.x); p[1] = (__bf16)(a0.y + b0.y);
            p[2] = (__bf16)(a0.z + b0.z); p[3] = (__bf16)(a0.w + b0.w);
            p[4] = (__bf16)(a1.x + b1.x); p[5] = (__bf16)(a1.y + b1.y);
            p[6] = (__bf16)(a1.z + b1.z); p[7] = (__bf16)(a1.w + b1.w);
            int rb   = row >> 5;
            int kk   = kg >> 1;
            int slot = ((row & 31) + (kg & 1) * 32) ^ (kk & 7);
            *(bf16x8*)(zs + rb * 32768 + kk * 1024 + slot * 16) = p;
        }
    }
    __syncthreads();                               // only barrier

    const int lane16 = lane * 16;

#define LOADA(S, KK) \
    A0##S = *(const bf16x8*)(zs +         (KK) * 1024 + (lane16 ^ (((KK) & 7) << 4))); \
    A1##S = *(const bf16x8*)(zs + 32768 + (KK) * 1024 + (lane16 ^ (((KK) & 7) << 4)));
#define LOADB(S, KK) \
    B0##S = *(const bf16x8*)(bp0 + (KK) * 512); \
    B1##S = *(const bf16x8*)(bp1 + (KK) * 512); \
    B2##S = *(const bf16x8*)(bp2 + (KK) * 512); \
    B3##S = *(const bf16x8*)(bp3 + (KK) * 512);
#define STEP(S) \
    acc[0][0] = __builtin_amdgcn_mfma_f32_32x32x16_bf16(A0##S, B0##S, acc[0][0], 0, 0, 0); \
    acc[1][0] = __builtin_amdgcn_mfma_f32_32x32x16_bf16(A1##S, B0##S, acc[1][0], 0, 0, 0); \
    acc[0][1] = __builtin_amdgcn_mfma_f32_32x32x16_bf16(A0##S, B1##S, acc[0][1], 0, 0, 0); \
    acc[1][1] = __builtin_amdgcn_mfma_f32_32x32x16_bf16(A1##S, B1##S, acc[1][1], 0, 0, 0); \
    acc[0][2] = __builtin_amdgcn_mfma_f32_32x32x16_bf16(A0##S, B2##S, acc[0][2], 0, 0, 0); \
    acc[1][2] = __builtin_amdgcn_mfma_f32_32x32x16_bf16(A1##S, B2##S, acc[1][2], 0, 0, 0); \
    acc[0][3] = __builtin_amdgcn_mfma_f32_32x32x16_bf16(A0##S, B3##S, acc[0][3], 0, 0, 0); \
    acc[1][3] = __builtin_amdgcn_mfma_f32_32x32x16_bf16(A1##S, B3##S, acc[1][3], 0, 0, 0);

    // ---- phase 1: column loop, no barriers ----
    for (int ci = 0; ci < 4; ++ci) {
        const int cb   = ci * 4 + wv;
        const int colj = cb * 32 + l31;

        const __bf16* bp0 = Wp + ((size_t)(( 0 + cb) * 32)) * 512 + lane * 8;
        const __bf16* bp1 = Wp + ((size_t)((16 + cb) * 32)) * 512 + lane * 8;
        const __bf16* bp2 = Wp + ((size_t)((32 + cb) * 32)) * 512 + lane * 8;
        const __bf16* bp3 = Wp + ((size_t)((48 + cb) * 32)) * 512 + lane * 8;

        float bias0 = bfv[colj], bias1 = biv[colj], bias2 = bgv[colj], bias3 = bov[colj];
        f32x16 acc[2][4];
        #pragma unroll
        for (int m = 0; m < 2; ++m) {
            #pragma unroll
            for (int r = 0; r < 16; ++r) {
                acc[m][0][r] = bias0; acc[m][1][r] = bias1;
                acc[m][2][r] = bias2; acc[m][3][r] = bias3;
            }
        }

        bf16x8 A0a, A1a, B0a, B1a, B2a, B3a;
        bf16x8 A0b, A1b, B0b, B1b, B2b, B3b;

        LOADA(a, 0)
        LOADB(a, 0)
        #pragma unroll
        for (int kk = 0; kk < 32; kk += 2) {
            LOADA(b, kk + 1)
            LOADB(b, kk + 1)
            STEP(a)
            if (kk + 2 < 32) {
                LOADA(a, kk + 2)
                LOADB(a, kk + 2)
            }
            STEP(b)
        }

        // ---- epilogue: C/D layout col=l&31, row=(r&3)+8*(r>>2)+4*hi ----
        #pragma unroll
        for (int m = 0; m < 2; ++m) {
            #pragma unroll
            for (int r = 0; r < 16; ++r) {
                float F = acc[m][0][r], I = acc[m][1][r];
                float G = acc[m][2][r], O = acc[m][3][r];
                float c = fsigmoid(F) + fsigmoid(I) * ftanh(G);
                float h = ftanh(c) * fsigmoid(O);
                int row = row0 + m * 32 + (r & 3) + 8 * (r >> 2) + 4 * hi;
                int o   = row * 512 + colj;
                out[o] = c;
                out[33554432 + o] = h;             // h plane at 65536*512
            }
        }
    }
#undef LOADA
#undef LOADB
#undef STEP
}

extern "C" void kernel_launch(void* const* d_in, const int* in_sizes, int n_in,
                              void* d_out, int out_size, void* d_ws, size_t ws_size,
                              hipStream_t stream) {
    const float* xin = (const float*)d_in[0];
    const float* stm = (const float*)d_in[1];
    const float* Wf  = (const float*)d_in[2];
    const float* bf_ = (const float*)d_in[3];
    const float* Wi  = (const float*)d_in[4];
    const float* bi_ = (const float*)d_in[5];
    const float* Wg  = (const float*)d_in[6];
    const float* bg_ = (const float*)d_in[7];
    const float* Wo  = (const float*)d_in[8];
    const float* bo_ = (const float*)d_in[9];
    __bf16* Wp = (__bf16*)d_ws;                    // 2 MiB packed weights

    wpack<<<512, 256, 0, stream>>>(Wf, Wi, Wg, Wo, Wp);
    lstm_main<<<1024, 256, 0, stream>>>(xin, stm, Wp, bf_, bi_, bg_, bo_, (float*)d_out);
}

// Round 4
// 236.206 us; speedup vs baseline: 2.1325x; 2.1325x over previous
//
#include <hip/hip_runtime.h>

typedef __bf16 bf16x8 __attribute__((ext_vector_type(8)));
typedef float  f32x16 __attribute__((ext_vector_type(16)));

#define LOG2E 1.4426950408889634f

static __device__ __forceinline__ float fexp2(float x) { return __builtin_amdgcn_exp2f(x); }
static __device__ __forceinline__ float frcp(float x)  { return __builtin_amdgcn_rcpf(x); }
static __device__ __forceinline__ float fsigmoid(float x) { return frcp(1.0f + fexp2(-LOG2E * x)); }
static __device__ __forceinline__ float ftanh(float x)    { return 2.0f * frcp(1.0f + fexp2(-2.0f * LOG2E * x)) - 1.0f; }

// ---------------------------------------------------------------------------
// Prep: pack 4 [512x512] fp32 weights into bf16 MFMA-B-fragment-coalesced layout.
// Wp[((g*16+cb)*32+kk)*512 + lane*8 + e] = W_g[cb*32+(lane&31)][kk*16+(lane>>5)*8+e]
// ---------------------------------------------------------------------------
__global__ __launch_bounds__(256) void wpack(const float* __restrict__ Wf,
                                             const float* __restrict__ Wi,
                                             const float* __restrict__ Wg,
                                             const float* __restrict__ Wo,
                                             __bf16* __restrict__ Wp)
{
    int idx = blockIdx.x * 256 + threadIdx.x;      // [0, 131072)
    int kg  = idx & 63;                            // k-group of 8
    int j   = (idx >> 6) & 511;                    // weight row = output col
    int g   = idx >> 15;
    const float* src = (g == 0) ? Wf : (g == 1) ? Wi : (g == 2) ? Wg : Wo;
    const float4* s4 = (const float4*)(src + j * 512 + kg * 8);
    float4 v0 = s4[0], v1 = s4[1];
    bf16x8 o;
    o[0] = (__bf16)v0.x; o[1] = (__bf16)v0.y; o[2] = (__bf16)v0.z; o[3] = (__bf16)v0.w;
    o[4] = (__bf16)v1.x; o[5] = (__bf16)v1.y; o[6] = (__bf16)v1.z; o[7] = (__bf16)v1.w;
    int cb = j >> 5;
    int kk = kg >> 1;
    int lane_t = (j & 31) + (kg & 1) * 32;
    size_t dst = ((size_t)((g * 16 + cb) * 32 + kk)) * 512 + lane_t * 8;
    *(bf16x8*)(Wp + dst) = o;
}

// ---------------------------------------------------------------------------
// Main fused kernel. Block: 512 thr (8 waves), 64 rows, 64 KiB LDS.
// Wave wv: row-half mfr = wv&1 (32 rows), column group cg = wv>>1.
// Per wave: acc = 4 gates x 16 f32 = 64 regs -> fits 4 waves/SIMD (2 blocks/CU).
// ---------------------------------------------------------------------------
__global__ __launch_bounds__(512, 4) void lstm_main(
    const float* __restrict__ xin, const float* __restrict__ stm,
    const __bf16* __restrict__ Wp,
    const float* __restrict__ bfv, const float* __restrict__ biv,
    const float* __restrict__ bgv, const float* __restrict__ bov,
    float* __restrict__ out)
{
    __shared__ unsigned char zs[65536];            // 64 rows x 512 k, bf16, frag order
    const int tid  = threadIdx.x;
    const int lane = tid & 63;
    const int wv   = tid >> 6;                     // 0..7
    const int cg   = wv >> 1;                      // 0..3 column group
    const int mfr  = wv & 1;                       // 0..1 row half
    const int l31  = lane & 31;
    const int hi   = lane >> 5;
    const int row0 = blockIdx.x * 64;

    // ---- phase 0: z = x + stm -> bf16 -> LDS in fragment order ----
    {
        const float* xb = xin + (size_t)row0 * 512;
        const float* sb = stm + (size_t)row0 * 512;
        #pragma unroll
        for (int it = 0; it < 8; ++it) {
            int idx = it * 512 + tid;              // [0, 4096): 64 rows x 64 kgroups
            int row = idx >> 6;
            int kg  = idx & 63;
            const float4* x4 = (const float4*)(xb + row * 512 + kg * 8);
            const float4* s4 = (const float4*)(sb + row * 512 + kg * 8);
            float4 a0 = x4[0], a1 = x4[1];
            float4 b0 = s4[0], b1 = s4[1];
            bf16x8 p;
            p[0] = (__bf16)(a0.x + b0.x); p[1] = (__bf16)(a0.y + b0.y);
            p[2] = (__bf16)(a0.z + b0.z); p[3] = (__bf16)(a0.w + b0.w);
            p[4] = (__bf16)(a1.x + b1.x); p[5] = (__bf16)(a1.y + b1.y);
            p[6] = (__bf16)(a1.z + b1.z); p[7] = (__bf16)(a1.w + b1.w);
            int rb   = row >> 5;
            int kk   = kg >> 1;
            int slot = ((row & 31) + (kg & 1) * 32) ^ (kk & 7);
            *(bf16x8*)(zs + rb * 32768 + kk * 1024 + slot * 16) = p;
        }
    }
    __syncthreads();                               // only barrier

    const int lane16 = lane * 16;
    const int abase  = mfr * 32768;

    // ---- phase 1: column loop, no barriers ----
    for (int ci = 0; ci < 4; ++ci) {
        const int cb   = ci * 4 + cg;
        const int colj = cb * 32 + l31;

        const __bf16* bp0 = Wp + ((size_t)(( 0 + cb) * 32)) * 512 + lane * 8;
        const __bf16* bp1 = Wp + ((size_t)((16 + cb) * 32)) * 512 + lane * 8;
        const __bf16* bp2 = Wp + ((size_t)((32 + cb) * 32)) * 512 + lane * 8;
        const __bf16* bp3 = Wp + ((size_t)((48 + cb) * 32)) * 512 + lane * 8;

        float bias0 = bfv[colj], bias1 = biv[colj], bias2 = bgv[colj], bias3 = bov[colj];
        f32x16 acc[4];
        #pragma unroll
        for (int r = 0; r < 16; ++r) {
            acc[0][r] = bias0; acc[1][r] = bias1;
            acc[2][r] = bias2; acc[3][r] = bias3;
        }

        #pragma unroll 4
        for (int kk = 0; kk < 32; ++kk) {
            bf16x8 a  = *(const bf16x8*)(zs + abase + kk * 1024 + (lane16 ^ ((kk & 7) << 4)));
            bf16x8 b0 = *(const bf16x8*)(bp0 + kk * 512);
            bf16x8 b1 = *(const bf16x8*)(bp1 + kk * 512);
            bf16x8 b2 = *(const bf16x8*)(bp2 + kk * 512);
            bf16x8 b3 = *(const bf16x8*)(bp3 + kk * 512);
            acc[0] = __builtin_amdgcn_mfma_f32_32x32x16_bf16(a, b0, acc[0], 0, 0, 0);
            acc[1] = __builtin_amdgcn_mfma_f32_32x32x16_bf16(a, b1, acc[1], 0, 0, 0);
            acc[2] = __builtin_amdgcn_mfma_f32_32x32x16_bf16(a, b2, acc[2], 0, 0, 0);
            acc[3] = __builtin_amdgcn_mfma_f32_32x32x16_bf16(a, b3, acc[3], 0, 0, 0);
        }

        // ---- epilogue: C/D layout col=l&31, row=(r&3)+8*(r>>2)+4*hi ----
        #pragma unroll
        for (int r = 0; r < 16; ++r) {
            float F = acc[0][r], I = acc[1][r];
            float G = acc[2][r], O = acc[3][r];
            float c = fsigmoid(F) + fsigmoid(I) * ftanh(G);
            float h = ftanh(c) * fsigmoid(O);
            int row = row0 + mfr * 32 + (r & 3) + 8 * (r >> 2) + 4 * hi;
            int o   = row * 512 + colj;
            out[o] = c;
            out[33554432 + o] = h;                 // h plane at 65536*512
        }
    }
}

extern "C" void kernel_launch(void* const* d_in, const int* in_sizes, int n_in,
                              void* d_out, int out_size, void* d_ws, size_t ws_size,
                              hipStream_t stream) {
    const float* xin = (const float*)d_in[0];
    const float* stm = (const float*)d_in[1];
    const float* Wf  = (const float*)d_in[2];
    const float* bf_ = (const float*)d_in[3];
    const float* Wi  = (const float*)d_in[4];
    const float* bi_ = (const float*)d_in[5];
    const float* Wg  = (const float*)d_in[6];
    const float* bg_ = (const float*)d_in[7];
    const float* Wo  = (const float*)d_in[8];
    const float* bo_ = (const float*)d_in[9];
    __bf16* Wp = (__bf16*)d_ws;                    // 2 MiB packed weights

    wpack<<<512, 256, 0, stream>>>(Wf, Wi, Wg, Wo, Wp);
    lstm_main<<<1024, 512, 0, stream>>>(xin, stm, Wp, bf_, bi_, bg_, bo_, (float*)d_out);
}

// Round 5
// 234.516 us; speedup vs baseline: 2.1479x; 1.0072x over previous
//
#include <hip/hip_runtime.h>

typedef __bf16 bf16x8 __attribute__((ext_vector_type(8)));
typedef float  f32x4  __attribute__((ext_vector_type(4)));

#define LOG2E 1.4426950408889634f

static __device__ __forceinline__ float fexp2(float x) { return __builtin_amdgcn_exp2f(x); }
static __device__ __forceinline__ float frcp(float x)  { return __builtin_amdgcn_rcpf(x); }
static __device__ __forceinline__ float fsigmoid(float x) { return frcp(1.0f + fexp2(-LOG2E * x)); }
static __device__ __forceinline__ float ftanh(float x)    { return 2.0f * frcp(1.0f + fexp2(-2.0f * LOG2E * x)) - 1.0f; }

// ---------------------------------------------------------------------------
// Prep: pack 4 [512x512] fp32 weights into bf16 16x16x32-B-fragment order.
// Wp[(((g*32+cn)*16+ks)*64 + lane)*8 + e] = W_g[cn*16+(lane&15)][ks*32+(lane>>4)*8+e]
// so a wave's per-ks B load is base + ks*1024B + lane*16B (coalesced 1 KiB).
// ---------------------------------------------------------------------------
__global__ __launch_bounds__(256) void wpack(const float* __restrict__ Wf,
                                             const float* __restrict__ Wi,
                                             const float* __restrict__ Wg,
                                             const float* __restrict__ Wo,
                                             __bf16* __restrict__ Wp)
{
    int idx = blockIdx.x * 256 + threadIdx.x;      // [0, 131072)
    int kg  = idx & 63;                            // k-group of 8
    int j   = (idx >> 6) & 511;                    // weight row = output col
    int g   = idx >> 15;
    const float* src = (g == 0) ? Wf : (g == 1) ? Wi : (g == 2) ? Wg : Wo;
    const float4* s4 = (const float4*)(src + j * 512 + kg * 8);
    float4 v0 = s4[0], v1 = s4[1];
    bf16x8 o;
    o[0] = (__bf16)v0.x; o[1] = (__bf16)v0.y; o[2] = (__bf16)v0.z; o[3] = (__bf16)v0.w;
    o[4] = (__bf16)v1.x; o[5] = (__bf16)v1.y; o[6] = (__bf16)v1.z; o[7] = (__bf16)v1.w;
    int cn = j >> 4;                               // 16-col group
    int ks = kg >> 2;                              // K=32 step
    int lt = (j & 15) + (kg & 3) * 16;             // lane slot
    size_t dst = ((size_t)(((g * 32 + cn) * 16 + ks) * 64 + lt)) * 8;
    *(bf16x8*)(Wp + dst) = o;
}

// ---------------------------------------------------------------------------
// Main fused kernel. Block: 512 thr (8 waves), 64 rows, 64 KiB LDS.
// Each wave owns ALL 64 rows x 16 cols x 4 gates (16x16x32 MFMA):
// acc = 4m x 4g x 4 = 64 regs; B loaded once per block (no duplication);
// 16 MFMA per K-step per wave -> 4x the latency cover of round 4.
// ---------------------------------------------------------------------------
__global__ __launch_bounds__(512, 4) void lstm_main(
    const float* __restrict__ xin, const float* __restrict__ stm,
    const __bf16* __restrict__ Wp,
    const float* __restrict__ bfv, const float* __restrict__ biv,
    const float* __restrict__ bgv, const float* __restrict__ bov,
    float* __restrict__ out)
{
    __shared__ unsigned char zs[65536];            // 64 rows x 512 k, bf16, 32x32-frag order
    const int tid  = threadIdx.x;
    const int lane = tid & 63;
    const int wv   = tid >> 6;                     // 0..7
    const int l15  = lane & 15;
    const int lq   = lane >> 4;                    // 0..3
    const int row0 = blockIdx.x * 64;

    // ---- phase 0: z = x + stm -> bf16 -> LDS (unchanged, verified) ----
    {
        const float* xb = xin + (size_t)row0 * 512;
        const float* sb = stm + (size_t)row0 * 512;
        #pragma unroll
        for (int it = 0; it < 8; ++it) {
            int idx = it * 512 + tid;              // [0, 4096): 64 rows x 64 kgroups
            int row = idx >> 6;
            int kg  = idx & 63;
            const float4* x4 = (const float4*)(xb + row * 512 + kg * 8);
            const float4* s4 = (const float4*)(sb + row * 512 + kg * 8);
            float4 a0 = x4[0], a1 = x4[1];
            float4 b0 = s4[0], b1 = s4[1];
            bf16x8 p;
            p[0] = (__bf16)(a0.x + b0.x); p[1] = (__bf16)(a0.y + b0.y);
            p[2] = (__bf16)(a0.z + b0.z); p[3] = (__bf16)(a0.w + b0.w);
            p[4] = (__bf16)(a1.x + b1.x); p[5] = (__bf16)(a1.y + b1.y);
            p[6] = (__bf16)(a1.z + b1.z); p[7] = (__bf16)(a1.w + b1.w);
            int rb   = row >> 5;
            int kk   = kg >> 1;
            int slot = ((row & 31) + (kg & 1) * 32) ^ (kk & 7);
            *(bf16x8*)(zs + rb * 32768 + kk * 1024 + slot * 16) = p;
        }
    }
    __syncthreads();                               // only barrier

    // Per-lane A-read invariants (16x16x32 frag from 32x32-order LDS):
    // row = m*16 + l15, k = ks*32 + lq*8 -> kk = 2ks + (lq>>1), kgrp = lq&1,
    // slot = (l15 + kgrp*32 + (m&1)*16) ^ (kk&7), byte = (m>>1)*32768 + kk*1024 + slot*16
    const int kkoff = lq >> 1;                     // 0/1
    const int s0    = l15 + (lq & 1) * 32;         // bit4 always clear
    const int koffb = kkoff << 10;

    // ---- phase 1: column loop, no barriers ----
    for (int ci = 0; ci < 4; ++ci) {
        const int cn   = ci * 8 + wv;              // 16-col group [0,32)
        const int colj = cn * 16 + l15;

        const __bf16* bp0 = Wp + ((size_t)((  0 + cn) * 16)) * 512 + lane * 8;
        const __bf16* bp1 = Wp + ((size_t)(( 32 + cn) * 16)) * 512 + lane * 8;
        const __bf16* bp2 = Wp + ((size_t)(( 64 + cn) * 16)) * 512 + lane * 8;
        const __bf16* bp3 = Wp + ((size_t)(( 96 + cn) * 16)) * 512 + lane * 8;

        float bias0 = bfv[colj], bias1 = biv[colj], bias2 = bgv[colj], bias3 = bov[colj];
        f32x4 acc[4][4];                           // [m][gate]
        #pragma unroll
        for (int m = 0; m < 4; ++m) {
            #pragma unroll
            for (int r = 0; r < 4; ++r) {
                acc[m][0][r] = bias0; acc[m][1][r] = bias1;
                acc[m][2][r] = bias2; acc[m][3][r] = bias3;
            }
        }

        #pragma unroll 4
        for (int ks = 0; ks < 16; ++ks) {
            const int kk7 = ((2 * ks) & 7) | kkoff;
            const int t0  = ((s0 ^ kk7) << 4) + ks * 2048 + koffb;
            bf16x8 a0 = *(const bf16x8*)(zs + t0);
            bf16x8 a1 = *(const bf16x8*)(zs + t0 + 256);
            bf16x8 a2 = *(const bf16x8*)(zs + t0 + 32768);
            bf16x8 a3 = *(const bf16x8*)(zs + t0 + 32768 + 256);
            bf16x8 b0 = *(const bf16x8*)(bp0 + ks * 512);
            bf16x8 b1 = *(const bf16x8*)(bp1 + ks * 512);
            bf16x8 b2 = *(const bf16x8*)(bp2 + ks * 512);
            bf16x8 b3 = *(const bf16x8*)(bp3 + ks * 512);
            acc[0][0] = __builtin_amdgcn_mfma_f32_16x16x32_bf16(a0, b0, acc[0][0], 0, 0, 0);
            acc[1][0] = __builtin_amdgcn_mfma_f32_16x16x32_bf16(a1, b0, acc[1][0], 0, 0, 0);
            acc[2][0] = __builtin_amdgcn_mfma_f32_16x16x32_bf16(a2, b0, acc[2][0], 0, 0, 0);
            acc[3][0] = __builtin_amdgcn_mfma_f32_16x16x32_bf16(a3, b0, acc[3][0], 0, 0, 0);
            acc[0][1] = __builtin_amdgcn_mfma_f32_16x16x32_bf16(a0, b1, acc[0][1], 0, 0, 0);
            acc[1][1] = __builtin_amdgcn_mfma_f32_16x16x32_bf16(a1, b1, acc[1][1], 0, 0, 0);
            acc[2][1] = __builtin_amdgcn_mfma_f32_16x16x32_bf16(a2, b1, acc[2][1], 0, 0, 0);
            acc[3][1] = __builtin_amdgcn_mfma_f32_16x16x32_bf16(a3, b1, acc[3][1], 0, 0, 0);
            acc[0][2] = __builtin_amdgcn_mfma_f32_16x16x32_bf16(a0, b2, acc[0][2], 0, 0, 0);
            acc[1][2] = __builtin_amdgcn_mfma_f32_16x16x32_bf16(a1, b2, acc[1][2], 0, 0, 0);
            acc[2][2] = __builtin_amdgcn_mfma_f32_16x16x32_bf16(a2, b2, acc[2][2], 0, 0, 0);
            acc[3][2] = __builtin_amdgcn_mfma_f32_16x16x32_bf16(a3, b2, acc[3][2], 0, 0, 0);
            acc[0][3] = __builtin_amdgcn_mfma_f32_16x16x32_bf16(a0, b3, acc[0][3], 0, 0, 0);
            acc[1][3] = __builtin_amdgcn_mfma_f32_16x16x32_bf16(a1, b3, acc[1][3], 0, 0, 0);
            acc[2][3] = __builtin_amdgcn_mfma_f32_16x16x32_bf16(a2, b3, acc[2][3], 0, 0, 0);
            acc[3][3] = __builtin_amdgcn_mfma_f32_16x16x32_bf16(a3, b3, acc[3][3], 0, 0, 0);
        }

        // ---- epilogue: 16x16 C/D layout col=l&15, row=(l>>4)*4+r ----
        #pragma unroll
        for (int m = 0; m < 4; ++m) {
            #pragma unroll
            for (int r = 0; r < 4; ++r) {
                float F = acc[m][0][r], I = acc[m][1][r];
                float G = acc[m][2][r], O = acc[m][3][r];
                float c = fsigmoid(F) + fsigmoid(I) * ftanh(G);
                float h = ftanh(c) * fsigmoid(O);
                int row = row0 + m * 16 + lq * 4 + r;
                int o   = row * 512 + colj;
                out[o] = c;
                out[33554432 + o] = h;             // h plane at 65536*512
            }
        }
    }
}

extern "C" void kernel_launch(void* const* d_in, const int* in_sizes, int n_in,
                              void* d_out, int out_size, void* d_ws, size_t ws_size,
                              hipStream_t stream) {
    const float* xin = (const float*)d_in[0];
    const float* stm = (const float*)d_in[1];
    const float* Wf  = (const float*)d_in[2];
    const float* bf_ = (const float*)d_in[3];
    const float* Wi  = (const float*)d_in[4];
    const float* bi_ = (const float*)d_in[5];
    const float* Wg  = (const float*)d_in[6];
    const float* bg_ = (const float*)d_in[7];
    const float* Wo  = (const float*)d_in[8];
    const float* bo_ = (const float*)d_in[9];
    __bf16* Wp = (__bf16*)d_ws;                    // 2 MiB packed weights

    wpack<<<512, 256, 0, stream>>>(Wf, Wi, Wg, Wo, Wp);
    lstm_main<<<1024, 512, 0, stream>>>(xin, stm, Wp, bf_, bi_, bg_, bo_, (float*)d_out);
}

// Round 6
// 192.906 us; speedup vs baseline: 2.6112x; 1.2157x over previous
//
#include <hip/hip_runtime.h>

typedef __bf16 bf16x8 __attribute__((ext_vector_type(8)));
typedef float  f32x4  __attribute__((ext_vector_type(4)));

#define LOG2E 1.4426950408889634f

static __device__ __forceinline__ float fexp2(float x) { return __builtin_amdgcn_exp2f(x); }
static __device__ __forceinline__ float frcp(float x)  { return __builtin_amdgcn_rcpf(x); }
static __device__ __forceinline__ float fsigmoid(float x) { return frcp(1.0f + fexp2(-LOG2E * x)); }
static __device__ __forceinline__ float ftanh(float x)    { return 2.0f * frcp(1.0f + fexp2(-2.0f * LOG2E * x)) - 1.0f; }

// ---------------------------------------------------------------------------
// Prep: pack 4 [512x512] fp32 weights into bf16 16x16x32-B-fragment order.
// Wp[(((g*32+cn)*16+ks)*64 + lane)*8 + e] = W_g[cn*16+(lane&15)][ks*32+(lane>>4)*8+e]
// ---------------------------------------------------------------------------
__global__ __launch_bounds__(256) void wpack(const float* __restrict__ Wf,
                                             const float* __restrict__ Wi,
                                             const float* __restrict__ Wg,
                                             const float* __restrict__ Wo,
                                             __bf16* __restrict__ Wp)
{
    int idx = blockIdx.x * 256 + threadIdx.x;      // [0, 131072)
    int kg  = idx & 63;                            // k-group of 8
    int j   = (idx >> 6) & 511;                    // weight row = output col
    int g   = idx >> 15;
    const float* src = (g == 0) ? Wf : (g == 1) ? Wi : (g == 2) ? Wg : Wo;
    const float4* s4 = (const float4*)(src + j * 512 + kg * 8);
    float4 v0 = s4[0], v1 = s4[1];
    bf16x8 o;
    o[0] = (__bf16)v0.x; o[1] = (__bf16)v0.y; o[2] = (__bf16)v0.z; o[3] = (__bf16)v0.w;
    o[4] = (__bf16)v1.x; o[5] = (__bf16)v1.y; o[6] = (__bf16)v1.z; o[7] = (__bf16)v1.w;
    int cn = j >> 4;                               // 16-col group
    int ks = kg >> 2;                              // K=32 step
    int lt = (j & 15) + (kg & 3) * 16;             // lane slot
    size_t dst = ((size_t)(((g * 32 + cn) * 16 + ks) * 64 + lt)) * 8;
    *(bf16x8*)(Wp + dst) = o;
}

// ---------------------------------------------------------------------------
// Main fused kernel. Block: 512 thr (8 waves), BM=128 rows, 128 KiB LDS.
// Each wave owns ALL 128 rows x 16 cols x 4 gates: acc = 8m x 4g x 4 = 128 regs,
// 32 MFMA per K-step per 4 B-loads -> B-from-L2 is 2.1x under the MFMA time.
// 1 block/CU (LDS), 2 waves/SIMD.
// ---------------------------------------------------------------------------
__global__ __launch_bounds__(512, 2) void lstm_main(
    const float* __restrict__ xin, const float* __restrict__ stm,
    const __bf16* __restrict__ Wp,
    const float* __restrict__ bfv, const float* __restrict__ biv,
    const float* __restrict__ bgv, const float* __restrict__ bov,
    float* __restrict__ out)
{
    __shared__ unsigned char zs[131072];           // 128 rows x 512 k, bf16, frag order
    const int tid  = threadIdx.x;
    const int lane = tid & 63;
    const int wv   = tid >> 6;                     // 0..7
    const int l15  = lane & 15;
    const int lq   = lane >> 4;                    // 0..3
    const int row0 = blockIdx.x * 128;

    // ---- phase 0: z = x + stm -> bf16 -> LDS (layout identical to verified r5) ----
    {
        const float* xb = xin + (size_t)row0 * 512;
        const float* sb = stm + (size_t)row0 * 512;
        #pragma unroll
        for (int it = 0; it < 16; ++it) {
            int idx = it * 512 + tid;              // [0, 8192): 128 rows x 64 kgroups
            int row = idx >> 6;
            int kg  = idx & 63;
            const float4* x4 = (const float4*)(xb + row * 512 + kg * 8);
            const float4* s4 = (const float4*)(sb + row * 512 + kg * 8);
            float4 a0 = x4[0], a1 = x4[1];
            float4 b0 = s4[0], b1 = s4[1];
            bf16x8 p;
            p[0] = (__bf16)(a0.x + b0.x); p[1] = (__bf16)(a0.y + b0.y);
            p[2] = (__bf16)(a0.z + b0.z); p[3] = (__bf16)(a0.w + b0.w);
            p[4] = (__bf16)(a1.x + b1.x); p[5] = (__bf16)(a1.y + b1.y);
            p[6] = (__bf16)(a1.z + b1.z); p[7] = (__bf16)(a1.w + b1.w);
            int rb   = row >> 5;                   // 0..3 chunk (32 KiB each)
            int kk   = kg >> 1;
            int slot = ((row & 31) + (kg & 1) * 32) ^ (kk & 7);
            *(bf16x8*)(zs + rb * 32768 + kk * 1024 + slot * 16) = p;
        }
    }
    __syncthreads();                               // only barrier

    // A-read (16x16x32 frag): row = m*16+l15, k = ks*32+lq*8
    // kk = 2ks+(lq>>1), slot = (l15 + (m&1)*16 + (lq&1)*32) ^ (kk&7)
    // byte = (m>>1)*32768 + kk*1024 + slot*16  (XOR affects only bits 0-2 of slot)
    const int kkoff = lq >> 1;                     // 0/1
    const int s0    = l15 + (lq & 1) * 32;         // bit4 clear
    const int koffb = kkoff << 10;

    // ---- phase 1: column loop, no barriers ----
    for (int ci = 0; ci < 4; ++ci) {
        const int cn   = ci * 8 + wv;              // 16-col group [0,32)
        const int colj = cn * 16 + l15;

        const __bf16* bp0 = Wp + ((size_t)((  0 + cn) * 16)) * 512 + lane * 8;
        const __bf16* bp1 = Wp + ((size_t)(( 32 + cn) * 16)) * 512 + lane * 8;
        const __bf16* bp2 = Wp + ((size_t)(( 64 + cn) * 16)) * 512 + lane * 8;
        const __bf16* bp3 = Wp + ((size_t)(( 96 + cn) * 16)) * 512 + lane * 8;

        float bias0 = bfv[colj], bias1 = biv[colj], bias2 = bgv[colj], bias3 = bov[colj];
        f32x4 acc[8][4];                           // [m][gate] = 128 regs
        #pragma unroll
        for (int m = 0; m < 8; ++m) {
            #pragma unroll
            for (int r = 0; r < 4; ++r) {
                acc[m][0][r] = bias0; acc[m][1][r] = bias1;
                acc[m][2][r] = bias2; acc[m][3][r] = bias3;
            }
        }

        #pragma unroll 2
        for (int ks = 0; ks < 16; ++ks) {
            const int kk7 = ((2 * ks) & 7) | kkoff;
            const int t0  = ((s0 ^ kk7) << 4) + ks * 2048 + koffb;
            bf16x8 b0 = *(const bf16x8*)(bp0 + ks * 512);
            bf16x8 b1 = *(const bf16x8*)(bp1 + ks * 512);
            bf16x8 b2 = *(const bf16x8*)(bp2 + ks * 512);
            bf16x8 b3 = *(const bf16x8*)(bp3 + ks * 512);
            bf16x8 a[8];
            #pragma unroll
            for (int m = 0; m < 8; ++m)
                a[m] = *(const bf16x8*)(zs + (m >> 1) * 32768 + (m & 1) * 256 + t0);
            #pragma unroll
            for (int m = 0; m < 8; ++m) {
                acc[m][0] = __builtin_amdgcn_mfma_f32_16x16x32_bf16(a[m], b0, acc[m][0], 0, 0, 0);
                acc[m][1] = __builtin_amdgcn_mfma_f32_16x16x32_bf16(a[m], b1, acc[m][1], 0, 0, 0);
                acc[m][2] = __builtin_amdgcn_mfma_f32_16x16x32_bf16(a[m], b2, acc[m][2], 0, 0, 0);
                acc[m][3] = __builtin_amdgcn_mfma_f32_16x16x32_bf16(a[m], b3, acc[m][3], 0, 0, 0);
            }
        }

        // ---- epilogue: 16x16 C/D layout col=l&15, row=lq*4+r ----
        #pragma unroll
        for (int m = 0; m < 8; ++m) {
            #pragma unroll
            for (int r = 0; r < 4; ++r) {
                float F = acc[m][0][r], I = acc[m][1][r];
                float G = acc[m][2][r], O = acc[m][3][r];
                float c = fsigmoid(F) + fsigmoid(I) * ftanh(G);
                float h = ftanh(c) * fsigmoid(O);
                int row = row0 + m * 16 + lq * 4 + r;
                int o   = row * 512 + colj;
                out[o] = c;
                out[33554432 + o] = h;             // h plane at 65536*512
            }
        }
    }
}

extern "C" void kernel_launch(void* const* d_in, const int* in_sizes, int n_in,
                              void* d_out, int out_size, void* d_ws, size_t ws_size,
                              hipStream_t stream) {
    const float* xin = (const float*)d_in[0];
    const float* stm = (const float*)d_in[1];
    const float* Wf  = (const float*)d_in[2];
    const float* bf_ = (const float*)d_in[3];
    const float* Wi  = (const float*)d_in[4];
    const float* bi_ = (const float*)d_in[5];
    const float* Wg  = (const float*)d_in[6];
    const float* bg_ = (const float*)d_in[7];
    const float* Wo  = (const float*)d_in[8];
    const float* bo_ = (const float*)d_in[9];
    __bf16* Wp = (__bf16*)d_ws;                    // 2 MiB packed weights

    wpack<<<512, 256, 0, stream>>>(Wf, Wi, Wg, Wo, Wp);
    lstm_main<<<512, 512, 0, stream>>>(xin, stm, Wp, bf_, bi_, bg_, bo_, (float*)d_out);
}